// Round 1
// baseline (465.943 us; speedup 1.0000x reference)
//
#include <hip/hip_runtime.h>
#include <math.h>

#define NB 4
#define SEQ 1024
#define DMODEL 1024
#define NHEAD 16
#define DHEAD 64

typedef __attribute__((ext_vector_type(8))) short s16x8;
typedef __attribute__((ext_vector_type(4))) short s16x4;
typedef __attribute__((ext_vector_type(4))) float f32x4;

__device__ __forceinline__ short f2bf(float f) {
    union { float f; unsigned u; } x; x.f = f;
    unsigned r = x.u + 0x7fffu + ((x.u >> 16) & 1u);   // RNE
    return (short)(r >> 16);
}

__device__ __forceinline__ unsigned pack2(float lo, float hi) {
    return ((unsigned)(unsigned short)f2bf(hi) << 16) | (unsigned)(unsigned short)f2bf(lo);
}

__device__ __forceinline__ f32x4 mfma16(s16x8 a, s16x8 b, f32x4 c) {
    return __builtin_amdgcn_mfma_f32_16x16x32_bf16(a, b, c, 0, 0, 0);
}

__device__ __forceinline__ s16x8 cvt8(float4 a, float4 b) {
    s16x8 v;
    v[0] = f2bf(a.x); v[1] = f2bf(a.y); v[2] = f2bf(a.z); v[3] = f2bf(a.w);
    v[4] = f2bf(b.x); v[5] = f2bf(b.y); v[6] = f2bf(b.z); v[7] = f2bf(b.w);
    return v;
}

// ---------------------------------------------------------------------------
// pos_proj: pe[l][t] (sinusoid, l-512) @ W_pos -> qp/kp1/kp2 [H][L][64] bf16
// grid: 3 sections * 128 l-groups of 8; block 256
// ---------------------------------------------------------------------------
__global__ __launch_bounds__(256) void pos_proj_kernel(
    const float* __restrict__ Wpos, short* __restrict__ qpb,
    short* __restrict__ kp1b, short* __restrict__ kp2b)
{
    int bid = blockIdx.x;
    int s = bid >> 7;             // 0..2
    int l0 = (bid & 127) * 8;
    int tid = threadIdx.x;
    __shared__ float pe[8][64];

    for (int idx = tid; idx < 512; idx += 256) {
        int li = idx >> 6, t = idx & 63;
        float p = (float)(l0 + li - 512);
        int j = (t < 32) ? t : (t - 32);
        float f = expf(-0.2971077539f * (float)j);   // ln(10000)/31
        float a = p * f;
        pe[li][t] = (t < 32) ? sinf(a) : cosf(a);
    }
    __syncthreads();

    float acc[4][8] = {};
    const float* wp = Wpos + s * 1024 + tid;
    for (int t = 0; t < 64; ++t) {
        float w0 = wp[t * 3072];
        float w1 = wp[t * 3072 + 256];
        float w2 = wp[t * 3072 + 512];
        float w3 = wp[t * 3072 + 768];
        #pragma unroll
        for (int li = 0; li < 8; ++li) {
            float pv = pe[li][t];
            acc[0][li] += pv * w0; acc[1][li] += pv * w1;
            acc[2][li] += pv * w2; acc[3][li] += pv * w3;
        }
    }
    short* dst = (s == 0) ? qpb : (s == 1) ? kp1b : kp2b;
    #pragma unroll
    for (int cc = 0; cc < 4; ++cc) {
        int c = tid + cc * 256;
        int h = c >> 6, d = c & 63;
        #pragma unroll
        for (int li = 0; li < 8; ++li) {
            dst[((size_t)(h << 10) + l0 + li) * 64 + d] = f2bf(acc[cc][li]);
        }
    }
}

// ---------------------------------------------------------------------------
// gemm_bt: C[M][NCOLS] = A[M][1024] (fp32 or bf16) @ B[1024][NCOLS] (fp32)
// bf16 MFMA 16x16x32, 128x128 block tile, BK=32, 4 waves (2x2 of 64x64).
// EPI==0: scatter to q/k1/k2 [B][H][L][64] and vT [B][H][64][L] (bf16)
// EPI==1: linear fp32 store to `of`
// ---------------------------------------------------------------------------
template<int EPI, int NCOLS, typename AT>
__global__ __launch_bounds__(256) void gemm_bt(
    const AT* __restrict__ A, const float* __restrict__ Bm,
    short* __restrict__ o0, short* __restrict__ o1, short* __restrict__ o2,
    short* __restrict__ o3, float* __restrict__ of)
{
    constexpr int KDIM = 1024;
    __shared__ short As[128][40];   // padded: row = 80 B (16B-aligned)
    __shared__ short Bs[128][40];   // B^T tile: [n][k]

    int tid = threadIdx.x;
    int m0 = blockIdx.y * 128, n0 = blockIdx.x * 128;
    int w = tid >> 6, lane = tid & 63;
    int wm = w >> 1, wn = w & 1;
    int lq = lane & 15, lg = lane >> 4;

    f32x4 zero = {0.f, 0.f, 0.f, 0.f};
    f32x4 acc[4][4];
    #pragma unroll
    for (int i = 0; i < 4; ++i)
        #pragma unroll
        for (int j = 0; j < 4; ++j) acc[i][j] = zero;

    int ar = tid >> 1, acb = (tid & 1) * 16;
    int bkg = tid >> 5, bnq = tid & 31;

    for (int kt = 0; kt < KDIM; kt += 32) {
        __syncthreads();
        {   // stage A tile [128][32]
            const AT* arow = A + (size_t)(m0 + ar) * KDIM + kt + acb;
            if constexpr (sizeof(AT) == 4) {
                float4 f0 = *(const float4*)(arow);
                float4 f1 = *(const float4*)(arow + 4);
                float4 f2 = *(const float4*)(arow + 8);
                float4 f3 = *(const float4*)(arow + 12);
                *(s16x8*)&As[ar][acb]     = cvt8(f0, f1);
                *(s16x8*)&As[ar][acb + 8] = cvt8(f2, f3);
            } else {
                *(uint4*)&As[ar][acb]     = *(const uint4*)(arow);
                *(uint4*)&As[ar][acb + 8] = *(const uint4*)(arow + 8);
            }
        }
        {   // stage B tile transposed: Bs[n][k]
            const float* bp = Bm + (size_t)(kt + bkg * 4) * NCOLS + n0 + bnq * 4;
            float4 r0 = *(const float4*)(bp);
            float4 r1 = *(const float4*)(bp + NCOLS);
            float4 r2 = *(const float4*)(bp + 2 * NCOLS);
            float4 r3 = *(const float4*)(bp + 3 * NCOLS);
            float rr[4][4] = {{r0.x, r1.x, r2.x, r3.x}, {r0.y, r1.y, r2.y, r3.y},
                              {r0.z, r1.z, r2.z, r3.z}, {r0.w, r1.w, r2.w, r3.w}};
            #pragma unroll
            for (int i = 0; i < 4; ++i) {
                s16x4 v;
                v[0] = f2bf(rr[i][0]); v[1] = f2bf(rr[i][1]);
                v[2] = f2bf(rr[i][2]); v[3] = f2bf(rr[i][3]);
                *(s16x4*)&Bs[bnq * 4 + i][bkg * 4] = v;
            }
        }
        __syncthreads();

        s16x8 af[4], bfr[4];
        #pragma unroll
        for (int mt = 0; mt < 4; ++mt)
            af[mt] = *(const s16x8*)&As[wm * 64 + mt * 16 + lq][lg * 8];
        #pragma unroll
        for (int nt = 0; nt < 4; ++nt)
            bfr[nt] = *(const s16x8*)&Bs[wn * 64 + nt * 16 + lq][lg * 8];
        #pragma unroll
        for (int mt = 0; mt < 4; ++mt)
            #pragma unroll
            for (int nt = 0; nt < 4; ++nt)
                acc[mt][nt] = mfma16(af[mt], bfr[nt], acc[mt][nt]);
    }

    // epilogue: D row = m-side (lg*4+r), col = n-side (lq)
    #pragma unroll
    for (int nt = 0; nt < 4; ++nt) {
        int n = n0 + wn * 64 + nt * 16 + lq;
        #pragma unroll
        for (int mt = 0; mt < 4; ++mt) {
            #pragma unroll
            for (int r = 0; r < 4; ++r) {
                int m = m0 + wm * 64 + mt * 16 + lg * 4 + r;
                float v = acc[mt][nt][r];
                if constexpr (EPI == 0) {
                    int b = m >> 10, li = m & 1023;
                    int sec = n >> 10, hd = n & 1023;
                    int hh = hd >> 6, d = hd & 63;
                    short bv = f2bf(v);
                    if (sec == 0)
                        o0[((size_t)((b * 16 + hh) << 10) + li) * 64 + d] = bv;
                    else if (sec == 1)
                        o1[((size_t)((b * 16 + hh) << 10) + li) * 64 + d] = bv;
                    else if (sec == 2)
                        o2[((size_t)((b * 16 + hh) << 10) + li) * 64 + d] = bv;
                    else
                        o3[((size_t)((b * 16 + hh) * 64 + d) << 10) + li] = bv;
                } else {
                    of[(size_t)m * NCOLS + n] = v;
                }
            }
        }
    }
}

// ---------------------------------------------------------------------------
// attn: flash attention; wave = 16 q rows; 32-k slabs; swapped QK^T
// S lane layout: lane holds S[q = lane&15][k = K0 + (lane>>4)*4 + r]
// ---------------------------------------------------------------------------
__global__ __launch_bounds__(256) void attn_kernel(
    const short* __restrict__ qb, const short* __restrict__ k1b,
    const short* __restrict__ k2b, const short* __restrict__ vtb,
    const short* __restrict__ qpb, const short* __restrict__ kp1b,
    const short* __restrict__ kp2b, const int* __restrict__ qmask,
    const int* __restrict__ umask, short* __restrict__ ctx)
{
    int qt = blockIdx.x, bh = blockIdx.y;
    int b = bh >> 4, h = bh & 15;
    int w = threadIdx.x >> 6, lane = threadIdx.x & 63;
    int lq = lane & 15, lg = lane >> 4;
    int q0 = qt * 64 + w * 16;
    int q_glob = q0 + lq;

    const short* qrow  = qb  + ((size_t)bh * SEQ + q0 + lq) * DHEAD;
    const short* qprow = qpb + ((size_t)h  * SEQ + q0 + lq) * DHEAD;
    s16x8 qf0  = *(const s16x8*)(qrow + lg * 8);
    s16x8 qf1  = *(const s16x8*)(qrow + 32 + lg * 8);
    s16x8 qpf0 = *(const s16x8*)(qprow + lg * 8);
    s16x8 qpf1 = *(const s16x8*)(qprow + 32 + lg * 8);
    int qm_q = qmask[b * SEQ + q_glob];

    const short* k1base  = k1b  + (size_t)bh * SEQ * DHEAD;
    const short* k2base  = k2b  + (size_t)bh * SEQ * DHEAD;
    const short* kp1base = kp1b + (size_t)h  * SEQ * DHEAD;
    const short* kp2base = kp2b + (size_t)h  * SEQ * DHEAD;
    const short* vbase   = vtb  + (size_t)bh * DHEAD * SEQ;
    const int* qmb = qmask + b * SEQ;
    const int* umb = umask + b * SEQ;

    f32x4 zero = {0.f, 0.f, 0.f, 0.f};
    f32x4 accO[4];
    #pragma unroll
    for (int i = 0; i < 4; ++i) accO[i] = zero;
    float m_run = -1e30f, l_run = 0.f;

    int nslab = (q0 + 47) >> 5;
    for (int ks = 0; ks < nslab; ++ks) {
        int K0 = ks << 5;
        f32x4 s1[2], s2[2];
        #pragma unroll
        for (int hh = 0; hh < 2; ++hh) {
            int krow = K0 + hh * 16 + lq;
            const short* kr   = k1base  + (size_t)krow * DHEAD;
            const short* kr2  = k2base  + (size_t)krow * DHEAD;
            const short* kpr  = kp1base + (size_t)krow * DHEAD;
            const short* kpr2 = kp2base + (size_t)krow * DHEAD;
            f32x4 t = zero;
            t = mfma16(*(const s16x8*)(kr + lg * 8), qf0, t);
            t = mfma16(*(const s16x8*)(kr + 32 + lg * 8), qf1, t);
            t = mfma16(*(const s16x8*)(kpr + lg * 8), qpf0, t);
            t = mfma16(*(const s16x8*)(kpr + 32 + lg * 8), qpf1, t);
            s1[hh] = t;
            f32x4 u = zero;
            u = mfma16(*(const s16x8*)(kr2 + lg * 8), qf0, u);
            u = mfma16(*(const s16x8*)(kr2 + 32 + lg * 8), qf1, u);
            u = mfma16(*(const s16x8*)(kpr2 + lg * 8), qpf0, u);
            u = mfma16(*(const s16x8*)(kpr2 + 32 + lg * 8), qpf1, u);
            s2[hh] = u;
        }
        int4 qmk0 = *(const int4*)(qmb + K0 + lg * 4);
        int4 qmk1 = *(const int4*)(qmb + K0 + 16 + lg * 4);
        int4 um0  = *(const int4*)(umb + K0 + lg * 4);
        int4 um1  = *(const int4*)(umb + K0 + 16 + lg * 4);
        int qmk[8] = {qmk0.x, qmk0.y, qmk0.z, qmk0.w, qmk1.x, qmk1.y, qmk1.z, qmk1.w};
        int umk[8] = {um0.x, um0.y, um0.z, um0.w, um1.x, um1.y, um1.z, um1.w};
        float sv[8];
        #pragma unroll
        for (int i = 0; i < 8; ++i) {
            int hh = i >> 2, r = i & 3;
            int k_idx = K0 + hh * 16 + lg * 4 + r;
            float s = (qmk[i] == qm_q) ? s1[hh][r] : s2[hh][r];
            if (k_idx > q_glob || umk[i] == 0) s = -INFINITY;
            sv[i] = s;
        }
        float tm = sv[0];
        #pragma unroll
        for (int i = 1; i < 8; ++i) tm = fmaxf(tm, sv[i]);
        tm = fmaxf(tm, __shfl_xor(tm, 16));
        tm = fmaxf(tm, __shfl_xor(tm, 32));
        float m_new = fmaxf(m_run, tm);
        float scale = __expf(m_run - m_new);
        float p[8]; float ps = 0.f;
        #pragma unroll
        for (int i = 0; i < 8; ++i) { p[i] = __expf(sv[i] - m_new); ps += p[i]; }
        ps += __shfl_xor(ps, 16);
        ps += __shfl_xor(ps, 32);
        l_run = l_run * scale + ps;
        m_run = m_new;

        f32x4 scv;
        scv[0] = __shfl(scale, lg * 4 + 0);
        scv[1] = __shfl(scale, lg * 4 + 1);
        scv[2] = __shfl(scale, lg * 4 + 2);
        scv[3] = __shfl(scale, lg * 4 + 3);
        #pragma unroll
        for (int dt = 0; dt < 4; ++dt) accO[dt] *= scv;

        // redistribute P into 16x16x32 A-operand layout (k = lg*8 + j)
        unsigned dA0 = pack2(p[0], p[1]);
        unsigned dA1 = pack2(p[2], p[3]);
        unsigned dB0 = pack2(p[4], p[5]);
        unsigned dB1 = pack2(p[6], p[7]);
        int sl0 = lq + ((lg & 1) << 5);
        int sl1 = sl0 + 16;
        unsigned a0 = (unsigned)__shfl((int)dA0, sl0), a1 = (unsigned)__shfl((int)dA1, sl0);
        unsigned a2 = (unsigned)__shfl((int)dA0, sl1), a3 = (unsigned)__shfl((int)dA1, sl1);
        unsigned c0 = (unsigned)__shfl((int)dB0, sl0), c1 = (unsigned)__shfl((int)dB1, sl0);
        unsigned c2 = (unsigned)__shfl((int)dB0, sl1), c3 = (unsigned)__shfl((int)dB1, sl1);
        bool hi = (lg >= 2);
        union { unsigned u[4]; s16x8 v; } pa;
        pa.u[0] = hi ? c0 : a0; pa.u[1] = hi ? c1 : a1;
        pa.u[2] = hi ? c2 : a2; pa.u[3] = hi ? c3 : a3;

        #pragma unroll
        for (int dt = 0; dt < 4; ++dt) {
            const short* vr = vbase + (size_t)(dt * 16 + lq) * SEQ + K0 + lg * 8;
            accO[dt] = mfma16(pa.v, *(const s16x8*)vr, accO[dt]);
        }
    }

    float inv = 1.0f / l_run;
    f32x4 invv;
    invv[0] = __shfl(inv, lg * 4 + 0);
    invv[1] = __shfl(inv, lg * 4 + 1);
    invv[2] = __shfl(inv, lg * 4 + 2);
    invv[3] = __shfl(inv, lg * 4 + 3);
    #pragma unroll
    for (int dt = 0; dt < 4; ++dt) {
        #pragma unroll
        for (int r = 0; r < 4; ++r) {
            int qo = q0 + lg * 4 + r;
            size_t off = ((size_t)(b * SEQ + qo)) * DMODEL + h * DHEAD + dt * 16 + lq;
            ctx[off] = f2bf(accO[dt][r] * invv[r]);
        }
    }
}

// ---------------------------------------------------------------------------
extern "C" void kernel_launch(void* const* d_in, const int* in_sizes, int n_in,
                              void* d_out, int out_size, void* d_ws, size_t ws_size,
                              hipStream_t stream) {
    const float* embed = (const float*)d_in[0];
    const int*   umask = (const int*)d_in[1];
    const int*   qmask = (const int*)d_in[2];
    const float* Wqkv  = (const float*)d_in[3];
    const float* Wpos  = (const float*)d_in[4];
    const float* Wfc   = (const float*)d_in[5];
    float* out = (float*)d_out;

    char* w = (char*)d_ws;
    short* qb   = (short*)(w + (0ull  << 20));  // [B][H][L][64]  8 MB
    short* k1b  = (short*)(w + (8ull  << 20));  // 8 MB
    short* k2b  = (short*)(w + (16ull << 20));  // 8 MB
    short* vtb  = (short*)(w + (24ull << 20));  // [B][H][64][L]  8 MB
    short* qpb  = (short*)(w + (32ull << 20));  // [H][L][64]     2 MB
    short* kp1b = (short*)(w + (34ull << 20));  // 2 MB
    short* kp2b = (short*)(w + (36ull << 20));  // 2 MB
    short* ctx  = (short*)(w + (38ull << 20));  // [B*L][1024]    8 MB  (end 46 MB)

    hipLaunchKernelGGL(pos_proj_kernel, dim3(384), dim3(256), 0, stream,
                       Wpos, qpb, kp1b, kp2b);
    hipLaunchKernelGGL((gemm_bt<0, 4096, float>), dim3(32, 32), dim3(256), 0, stream,
                       embed, Wqkv, qb, k1b, k2b, vtb, (float*)nullptr);
    hipLaunchKernelGGL(attn_kernel, dim3(16, 64), dim3(256), 0, stream,
                       qb, k1b, k2b, vtb, qpb, kp1b, kp2b, qmask, umask, ctx);
    hipLaunchKernelGGL((gemm_bt<1, 1024, short>), dim3(8, 32), dim3(256), 0, stream,
                       ctx, Wfc, (short*)nullptr, (short*)nullptr, (short*)nullptr,
                       (short*)nullptr, out);
}

// Round 2
// 262.659 us; speedup vs baseline: 1.7739x; 1.7739x over previous
//
#include <hip/hip_runtime.h>
#include <math.h>

#define NB 4
#define SEQ 1024
#define DMODEL 1024
#define NHEAD 16
#define DHEAD 64

typedef __attribute__((ext_vector_type(8))) short s16x8;
typedef __attribute__((ext_vector_type(4))) short s16x4;
typedef __attribute__((ext_vector_type(4))) float f32x4;

__device__ __forceinline__ short f2bf(float f) {
    union { float f; unsigned u; } x; x.f = f;
    unsigned r = x.u + 0x7fffu + ((x.u >> 16) & 1u);   // RNE
    return (short)(r >> 16);
}

__device__ __forceinline__ unsigned pack2(float lo, float hi) {
    return ((unsigned)(unsigned short)f2bf(hi) << 16) | (unsigned)(unsigned short)f2bf(lo);
}

__device__ __forceinline__ f32x4 mfma16(s16x8 a, s16x8 b, f32x4 c) {
    return __builtin_amdgcn_mfma_f32_16x16x32_bf16(a, b, c, 0, 0, 0);
}

__device__ __forceinline__ s16x8 cvt8(float4 a, float4 b) {
    s16x8 v;
    v[0] = f2bf(a.x); v[1] = f2bf(a.y); v[2] = f2bf(a.z); v[3] = f2bf(a.w);
    v[4] = f2bf(b.x); v[5] = f2bf(b.y); v[6] = f2bf(b.z); v[7] = f2bf(b.w);
    return v;
}

__device__ __forceinline__ s16x8 ldlds(const short* base, int byteoff) {
    return *(const s16x8*)((const char*)base + byteoff);
}

#define GLDS16(g, l) __builtin_amdgcn_global_load_lds( \
    (const __attribute__((address_space(1))) unsigned int*)(g), \
    (__attribute__((address_space(3))) unsigned int*)(l), 16, 0, 0)
#define GLDS4(g, l) __builtin_amdgcn_global_load_lds( \
    (const __attribute__((address_space(1))) unsigned int*)(g), \
    (__attribute__((address_space(3))) unsigned int*)(l), 4, 0, 0)

// ---------------------------------------------------------------------------
// mask_pack: PM[b][k] = qmask bit0 | (invalid << 1); 64-entry pad per batch
// ---------------------------------------------------------------------------
__global__ __launch_bounds__(256) void mask_pack_kernel(
    const int* __restrict__ qmask, const int* __restrict__ umask,
    int* __restrict__ PM)
{
    int b = blockIdx.x;
    for (int k = threadIdx.x; k < 1088; k += 256) {
        int v = 2;
        if (k < 1024)
            v = (qmask[b * 1024 + k] & 1) | ((umask[b * 1024 + k] == 0) ? 2 : 0);
        PM[b * 1088 + k] = v;
    }
}

// ---------------------------------------------------------------------------
// pos_proj: sinusoid table @ W_pos -> qpb [H][L][64]; kp1/kp2 broadcast into
// cols 64..127 of k1cat/k2cat [B][H][L][128]
// ---------------------------------------------------------------------------
__global__ __launch_bounds__(256) void pos_proj_kernel(
    const float* __restrict__ Wpos, short* __restrict__ qpb,
    short* __restrict__ k1cat, short* __restrict__ k2cat)
{
    int bid = blockIdx.x;
    int s = bid >> 7;             // 0..2
    int l0 = (bid & 127) * 8;
    int tid = threadIdx.x;
    __shared__ float pe[8][64];

    for (int idx = tid; idx < 512; idx += 256) {
        int li = idx >> 6, t = idx & 63;
        float p = (float)(l0 + li - 512);
        int j = (t < 32) ? t : (t - 32);
        float f = expf(-0.2971077539f * (float)j);   // ln(10000)/31
        float a = p * f;
        pe[li][t] = (t < 32) ? sinf(a) : cosf(a);
    }
    __syncthreads();

    float acc[4][8] = {};
    const float* wp = Wpos + s * 1024 + tid;
    for (int t = 0; t < 64; ++t) {
        float w0 = wp[t * 3072];
        float w1 = wp[t * 3072 + 256];
        float w2 = wp[t * 3072 + 512];
        float w3 = wp[t * 3072 + 768];
        #pragma unroll
        for (int li = 0; li < 8; ++li) {
            float pv = pe[li][t];
            acc[0][li] += pv * w0; acc[1][li] += pv * w1;
            acc[2][li] += pv * w2; acc[3][li] += pv * w3;
        }
    }
    #pragma unroll
    for (int cc = 0; cc < 4; ++cc) {
        int c = tid + cc * 256;
        int h = c >> 6, d = c & 63;
        #pragma unroll
        for (int li = 0; li < 8; ++li) {
            short bv = f2bf(acc[cc][li]);
            if (s == 0) {
                qpb[((size_t)(h << 10) + l0 + li) * 64 + d] = bv;
            } else {
                short* dst = (s == 1) ? k1cat : k2cat;
                #pragma unroll
                for (int bb = 0; bb < 4; ++bb)
                    dst[((size_t)((bb * 16 + h) * 1024) + l0 + li) * 128 + 64 + d] = bv;
            }
        }
    }
}

// ---------------------------------------------------------------------------
// gemm_bt: C[M][NCOLS] = A[M][1024] @ B[1024][NCOLS] (fp32 weights)
// EPI==0: scatter q -> qb[B][H][L][64]; k1/k2 -> cols 0..63 of
//         k1cat/k2cat [B][H][L][128]; v -> vT [B][H][64][L]
// EPI==1: linear fp32 store
// ---------------------------------------------------------------------------
template<int EPI, int NCOLS, typename AT>
__global__ __launch_bounds__(256) void gemm_bt(
    const AT* __restrict__ A, const float* __restrict__ Bm,
    short* __restrict__ o0, short* __restrict__ o1, short* __restrict__ o2,
    short* __restrict__ o3, float* __restrict__ of)
{
    constexpr int KDIM = 1024;
    __shared__ short As[128][40];
    __shared__ short Bs[128][40];

    int tid = threadIdx.x;
    int m0 = blockIdx.y * 128, n0 = blockIdx.x * 128;
    int w = tid >> 6, lane = tid & 63;
    int wm = w >> 1, wn = w & 1;
    int lq = lane & 15, lg = lane >> 4;

    f32x4 zero = {0.f, 0.f, 0.f, 0.f};
    f32x4 acc[4][4];
    #pragma unroll
    for (int i = 0; i < 4; ++i)
        #pragma unroll
        for (int j = 0; j < 4; ++j) acc[i][j] = zero;

    int ar = tid >> 1, acb = (tid & 1) * 16;
    int bkg = tid >> 5, bnq = tid & 31;

    for (int kt = 0; kt < KDIM; kt += 32) {
        __syncthreads();
        {
            const AT* arow = A + (size_t)(m0 + ar) * KDIM + kt + acb;
            if constexpr (sizeof(AT) == 4) {
                float4 f0 = *(const float4*)(arow);
                float4 f1 = *(const float4*)(arow + 4);
                float4 f2 = *(const float4*)(arow + 8);
                float4 f3 = *(const float4*)(arow + 12);
                *(s16x8*)&As[ar][acb]     = cvt8(f0, f1);
                *(s16x8*)&As[ar][acb + 8] = cvt8(f2, f3);
            } else {
                *(uint4*)&As[ar][acb]     = *(const uint4*)(arow);
                *(uint4*)&As[ar][acb + 8] = *(const uint4*)(arow + 8);
            }
        }
        {
            const float* bp = Bm + (size_t)(kt + bkg * 4) * NCOLS + n0 + bnq * 4;
            float4 r0 = *(const float4*)(bp);
            float4 r1 = *(const float4*)(bp + NCOLS);
            float4 r2 = *(const float4*)(bp + 2 * NCOLS);
            float4 r3 = *(const float4*)(bp + 3 * NCOLS);
            float rr[4][4] = {{r0.x, r1.x, r2.x, r3.x}, {r0.y, r1.y, r2.y, r3.y},
                              {r0.z, r1.z, r2.z, r3.z}, {r0.w, r1.w, r2.w, r3.w}};
            #pragma unroll
            for (int i = 0; i < 4; ++i) {
                s16x4 v;
                v[0] = f2bf(rr[i][0]); v[1] = f2bf(rr[i][1]);
                v[2] = f2bf(rr[i][2]); v[3] = f2bf(rr[i][3]);
                *(s16x4*)&Bs[bnq * 4 + i][bkg * 4] = v;
            }
        }
        __syncthreads();

        s16x8 af[4], bfr[4];
        #pragma unroll
        for (int mt = 0; mt < 4; ++mt)
            af[mt] = *(const s16x8*)&As[wm * 64 + mt * 16 + lq][lg * 8];
        #pragma unroll
        for (int nt = 0; nt < 4; ++nt)
            bfr[nt] = *(const s16x8*)&Bs[wn * 64 + nt * 16 + lq][lg * 8];
        #pragma unroll
        for (int mt = 0; mt < 4; ++mt)
            #pragma unroll
            for (int nt = 0; nt < 4; ++nt)
                acc[mt][nt] = mfma16(af[mt], bfr[nt], acc[mt][nt]);
    }

    #pragma unroll
    for (int nt = 0; nt < 4; ++nt) {
        int n = n0 + wn * 64 + nt * 16 + lq;
        #pragma unroll
        for (int mt = 0; mt < 4; ++mt) {
            #pragma unroll
            for (int r = 0; r < 4; ++r) {
                int m = m0 + wm * 64 + mt * 16 + lg * 4 + r;
                float v = acc[mt][nt][r];
                if constexpr (EPI == 0) {
                    int b = m >> 10, li = m & 1023;
                    int sec = n >> 10, hd = n & 1023;
                    int hh = hd >> 6, d = hd & 63;
                    int bh = b * 16 + hh;
                    short bv = f2bf(v);
                    if (sec == 0)
                        o0[((size_t)(bh << 10) + li) * 64 + d] = bv;
                    else if (sec == 1)
                        o1[((size_t)bh * 1024 + li) * 128 + d] = bv;
                    else if (sec == 2)
                        o2[((size_t)bh * 1024 + li) * 128 + d] = bv;
                    else
                        o3[((size_t)(bh * 64 + d) << 10) + li] = bv;
                } else {
                    of[(size_t)m * NCOLS + n] = v;
                }
            }
        }
    }
}

// ---------------------------------------------------------------------------
// attn: flash attention, 64 q rows / block (4 waves x 16), KVBLK=32 slabs
// staged into double-buffered LDS via global_load_lds, counted-vmcnt pipeline.
// ---------------------------------------------------------------------------
__global__ __launch_bounds__(256) void attn_kernel(
    const short* __restrict__ qb, const short* __restrict__ k1cat,
    const short* __restrict__ k2cat, const short* __restrict__ vtb,
    const short* __restrict__ qpb, const int* __restrict__ PM,
    const int* __restrict__ qmask, short* __restrict__ ctx)
{
    __shared__ short K1s[2][32 * 128];
    __shared__ short K2s[2][32 * 128];
    __shared__ short Vs[2][64 * 32];
    __shared__ int   PMs[2][64];

    int bid = blockIdx.x;
    int xg = bid & 7, jj = bid >> 3;
    int bh = xg * 8 + (jj & 7);      // XCD-clustered: one XCD works 8 bh panels
    int qt = jj >> 3;
    int b = bh >> 4, h = bh & 15;

    int w = threadIdx.x >> 6, lane = threadIdx.x & 63;
    int lq = lane & 15, lg = lane >> 4;
    int q0 = qt * 64 + w * 16;
    int q_glob = q0 + lq;

    // q fragments (128-dim cat: q | qp)
    const short* qrow  = qb  + ((size_t)bh * SEQ + q0 + lq) * DHEAD;
    const short* qprow = qpb + ((size_t)h  * SEQ + q0 + lq) * DHEAD;
    s16x8 qf0  = *(const s16x8*)(qrow + lg * 8);
    s16x8 qf1  = *(const s16x8*)(qrow + 32 + lg * 8);
    s16x8 qpf0 = *(const s16x8*)(qprow + lg * 8);
    s16x8 qpf1 = *(const s16x8*)(qprow + 32 + lg * 8);
    int qm_q = qmask[b * SEQ + q_glob] & 1;
    // drain q loads so loop vmcnt counts only staging ops
    asm volatile("s_waitcnt vmcnt(0)" ::: "memory");

    auto STAGE = [&](int d, int K0) {
        #pragma unroll
        for (int i = 0; i < 5; ++i) {
            int g = w * 5 + i;
            if (g < 8) {
                int row = g * 4 + (lane >> 4);
                int colb = ((lane & 15) << 4) ^ ((row & 7) << 4);
                const short* src = k1cat + ((size_t)bh * 1024 + K0 + row) * 128 + (colb >> 1);
                GLDS16(src, &K1s[d][g * 512]);
            } else if (g < 16) {
                int gg = g - 8;
                int row = gg * 4 + (lane >> 4);
                int colb = ((lane & 15) << 4) ^ ((row & 7) << 4);
                const short* src = k2cat + ((size_t)bh * 1024 + K0 + row) * 128 + (colb >> 1);
                GLDS16(src, &K2s[d][gg * 512]);
            } else {
                int c = g - 16;
                int row = c * 16 + (lane >> 2);
                int colb = ((lane & 3) << 4) ^ ((row & 3) << 4);
                const short* src = vtb + ((size_t)bh * 64 + row) * 1024 + K0 + (colb >> 1);
                GLDS16(src, &Vs[d][c * 512]);
            }
        }
        if (w == 0) {
            GLDS4(PM + b * 1088 + K0 + lane, &PMs[d][0]);
        }
    };

    f32x4 zero = {0.f, 0.f, 0.f, 0.f};
    f32x4 accO[4];
    #pragma unroll
    for (int i = 0; i < 4; ++i) accO[i] = zero;
    float m_run = -1e30f, l_run = 0.f;

    int nslab = 2 * qt + 2;
    STAGE(0, 0);

    for (int t = 0; t < nslab; ++t) {
        int cur = t & 1;
        if (t + 1 < nslab) {
            STAGE(cur ^ 1, (t + 1) * 32);
            if (w == 0) asm volatile("s_waitcnt vmcnt(6)" ::: "memory");
            else        asm volatile("s_waitcnt vmcnt(5)" ::: "memory");
        } else {
            asm volatile("s_waitcnt vmcnt(0)" ::: "memory");
        }
        __builtin_amdgcn_s_barrier();
        asm volatile("" ::: "memory");

        int K0 = t * 32;
        const short* b1 = K1s[cur];
        const short* b2 = K2s[cur];

        f32x4 s1v[2], s2v[2];
        #pragma unroll
        for (int hh = 0; hh < 2; ++hh) {
            int row = hh * 16 + lq;
            int ro = row * 256 + (lg << 4);
            int sw = (row & 7) << 4;
            f32x4 tv = zero, uv = zero;
            tv = mfma16(ldlds(b1, (ro      ) ^ sw), qf0,  tv);
            tv = mfma16(ldlds(b1, (ro +  64) ^ sw), qf1,  tv);
            tv = mfma16(ldlds(b1, (ro + 128) ^ sw), qpf0, tv);
            tv = mfma16(ldlds(b1, (ro + 192) ^ sw), qpf1, tv);
            s1v[hh] = tv;
            uv = mfma16(ldlds(b2, (ro      ) ^ sw), qf0,  uv);
            uv = mfma16(ldlds(b2, (ro +  64) ^ sw), qf1,  uv);
            uv = mfma16(ldlds(b2, (ro + 128) ^ sw), qpf0, uv);
            uv = mfma16(ldlds(b2, (ro + 192) ^ sw), qpf1, uv);
            s2v[hh] = uv;
        }

        float sv[8];
        #pragma unroll
        for (int i = 0; i < 8; ++i) {
            int hh = i >> 2, r = i & 3;
            int kl = hh * 16 + lg * 4 + r;
            int k_idx = K0 + kl;
            int pm = PMs[cur][kl];
            float s = ((pm & 1) == qm_q) ? s1v[hh][r] : s2v[hh][r];
            if (k_idx > q_glob || (pm & 2)) s = -INFINITY;
            sv[i] = s;
        }
        float tm = sv[0];
        #pragma unroll
        for (int i = 1; i < 8; ++i) tm = fmaxf(tm, sv[i]);
        tm = fmaxf(tm, __shfl_xor(tm, 16));
        tm = fmaxf(tm, __shfl_xor(tm, 32));
        float m_new = fmaxf(m_run, tm);
        float scale = __expf(m_run - m_new);
        float p[8]; float ps = 0.f;
        #pragma unroll
        for (int i = 0; i < 8; ++i) { p[i] = __expf(sv[i] - m_new); ps += p[i]; }
        ps += __shfl_xor(ps, 16);
        ps += __shfl_xor(ps, 32);
        l_run = l_run * scale + ps;
        m_run = m_new;

        f32x4 scv;
        scv[0] = __shfl(scale, lg * 4 + 0);
        scv[1] = __shfl(scale, lg * 4 + 1);
        scv[2] = __shfl(scale, lg * 4 + 2);
        scv[3] = __shfl(scale, lg * 4 + 3);
        #pragma unroll
        for (int dt = 0; dt < 4; ++dt) accO[dt] *= scv;

        // P -> 16x16x32 A-operand layout
        unsigned dA0 = pack2(p[0], p[1]);
        unsigned dA1 = pack2(p[2], p[3]);
        unsigned dB0 = pack2(p[4], p[5]);
        unsigned dB1 = pack2(p[6], p[7]);
        int sl0 = lq + ((lg & 1) << 5);
        int sl1 = sl0 + 16;
        unsigned a0 = (unsigned)__shfl((int)dA0, sl0), a1 = (unsigned)__shfl((int)dA1, sl0);
        unsigned a2 = (unsigned)__shfl((int)dA0, sl1), a3 = (unsigned)__shfl((int)dA1, sl1);
        unsigned c0 = (unsigned)__shfl((int)dB0, sl0), c1 = (unsigned)__shfl((int)dB1, sl0);
        unsigned c2 = (unsigned)__shfl((int)dB0, sl1), c3 = (unsigned)__shfl((int)dB1, sl1);
        bool hi = (lg >= 2);
        union { unsigned u[4]; s16x8 v; } pa;
        pa.u[0] = hi ? c0 : a0; pa.u[1] = hi ? c1 : a1;
        pa.u[2] = hi ? c2 : a2; pa.u[3] = hi ? c3 : a3;

        #pragma unroll
        for (int dt = 0; dt < 4; ++dt) {
            int vrow = dt * 16 + lq;
            int voff = (vrow * 64 + (lg << 4)) ^ ((vrow & 3) << 4);
            accO[dt] = mfma16(pa.v, ldlds(Vs[cur], voff), accO[dt]);
        }

        asm volatile("" ::: "memory");
        __builtin_amdgcn_s_barrier();   // buf[cur] free for next prefetch
    }

    float inv = 1.0f / l_run;
    f32x4 invv;
    invv[0] = __shfl(inv, lg * 4 + 0);
    invv[1] = __shfl(inv, lg * 4 + 1);
    invv[2] = __shfl(inv, lg * 4 + 2);
    invv[3] = __shfl(inv, lg * 4 + 3);
    #pragma unroll
    for (int dt = 0; dt < 4; ++dt) {
        #pragma unroll
        for (int r = 0; r < 4; ++r) {
            int qo = q0 + lg * 4 + r;
            size_t off = ((size_t)(b * SEQ + qo)) * DMODEL + h * DHEAD + dt * 16 + lq;
            ctx[off] = f2bf(accO[dt][r] * invv[r]);
        }
    }
}

// ---------------------------------------------------------------------------
extern "C" void kernel_launch(void* const* d_in, const int* in_sizes, int n_in,
                              void* d_out, int out_size, void* d_ws, size_t ws_size,
                              hipStream_t stream) {
    const float* embed = (const float*)d_in[0];
    const int*   umask = (const int*)d_in[1];
    const int*   qmask = (const int*)d_in[2];
    const float* Wqkv  = (const float*)d_in[3];
    const float* Wpos  = (const float*)d_in[4];
    const float* Wfc   = (const float*)d_in[5];
    float* out = (float*)d_out;

    char* w = (char*)d_ws;
    short* qb    = (short*)(w + (0ull  << 20));  // [B][H][L][64]    8 MB
    short* vtb   = (short*)(w + (8ull  << 20));  // [B][H][64][L]    8 MB
    short* qpb   = (short*)(w + (16ull << 20));  // [H][L][64]       2 MB
    short* ctx   = (short*)(w + (18ull << 20));  // [B*L][1024]      8 MB
    short* k1cat = (short*)(w + (26ull << 20));  // [B][H][L][128]  16 MB
    short* k2cat = (short*)(w + (42ull << 20));  // [B][H][L][128]  16 MB
    int*   PM    = (int*)  (w + (58ull << 20));  // [4][1088]       ~17 KB

    hipLaunchKernelGGL(mask_pack_kernel, dim3(4), dim3(256), 0, stream,
                       qmask, umask, PM);
    hipLaunchKernelGGL(pos_proj_kernel, dim3(384), dim3(256), 0, stream,
                       Wpos, qpb, k1cat, k2cat);
    hipLaunchKernelGGL((gemm_bt<0, 4096, float>), dim3(32, 32), dim3(256), 0, stream,
                       embed, Wqkv, qb, k1cat, k2cat, vtb, (float*)nullptr);
    hipLaunchKernelGGL(attn_kernel, dim3(1024), dim3(256), 0, stream,
                       qb, k1cat, k2cat, vtb, qpb, PM, qmask, ctx);
    hipLaunchKernelGGL((gemm_bt<1, 1024, short>), dim3(8, 32), dim3(256), 0, stream,
                       ctx, Wfc, (short*)nullptr, (short*)nullptr, (short*)nullptr,
                       (short*)nullptr, out);
}

// Round 3
// 201.576 us; speedup vs baseline: 2.3115x; 1.3030x over previous
//
#include <hip/hip_runtime.h>
#include <math.h>

#define NB 4
#define SEQ 1024
#define DMODEL 1024
#define NHEAD 16
#define DHEAD 64

typedef __attribute__((ext_vector_type(8))) short s16x8;
typedef __attribute__((ext_vector_type(4))) short s16x4;
typedef __attribute__((ext_vector_type(4))) float f32x4;

__device__ __forceinline__ short f2bf(float f) {
    union { float f; unsigned u; } x; x.f = f;
    unsigned r = x.u + 0x7fffu + ((x.u >> 16) & 1u);   // RNE
    return (short)(r >> 16);
}

__device__ __forceinline__ unsigned pack2(float lo, float hi) {
    return ((unsigned)(unsigned short)f2bf(hi) << 16) | (unsigned)(unsigned short)f2bf(lo);
}

__device__ __forceinline__ f32x4 mfma16(s16x8 a, s16x8 b, f32x4 c) {
    return __builtin_amdgcn_mfma_f32_16x16x32_bf16(a, b, c, 0, 0, 0);
}

__device__ __forceinline__ s16x8 cvt8(float4 a, float4 b) {
    s16x8 v;
    v[0] = f2bf(a.x); v[1] = f2bf(a.y); v[2] = f2bf(a.z); v[3] = f2bf(a.w);
    v[4] = f2bf(b.x); v[5] = f2bf(b.y); v[6] = f2bf(b.z); v[7] = f2bf(b.w);
    return v;
}

__device__ __forceinline__ s16x8 ldlds(const short* base, int byteoff) {
    return *(const s16x8*)((const char*)base + byteoff);
}

#define GLDS16(g, l) __builtin_amdgcn_global_load_lds( \
    (const __attribute__((address_space(1))) unsigned int*)(g), \
    (__attribute__((address_space(3))) unsigned int*)(l), 16, 0, 0)
#define GLDS4(g, l) __builtin_amdgcn_global_load_lds( \
    (const __attribute__((address_space(1))) unsigned int*)(g), \
    (__attribute__((address_space(3))) unsigned int*)(l), 4, 0, 0)

// ---------------------------------------------------------------------------
// mask_pack: PM[b][k] = qmask bit0 | (invalid << 1); 64-entry pad per batch
// ---------------------------------------------------------------------------
__global__ __launch_bounds__(256) void mask_pack_kernel(
    const int* __restrict__ qmask, const int* __restrict__ umask,
    int* __restrict__ PM)
{
    int b = blockIdx.x;
    for (int k = threadIdx.x; k < 1088; k += 256) {
        int v = 2;
        if (k < 1024)
            v = (qmask[b * 1024 + k] & 1) | ((umask[b * 1024 + k] == 0) ? 2 : 0);
        PM[b * 1088 + k] = v;
    }
}

// ---------------------------------------------------------------------------
// convert_embed: fp32 -> bf16 elementwise (8 els/thread, coalesced)
// ---------------------------------------------------------------------------
__global__ __launch_bounds__(256) void convert_embed_kernel(
    const float* __restrict__ src, short* __restrict__ dst)
{
    int i = (blockIdx.x * 256 + threadIdx.x) * 8;
    float4 a = *(const float4*)(src + i);
    float4 b = *(const float4*)(src + i + 4);
    *(s16x8*)(dst + i) = cvt8(a, b);
}

// ---------------------------------------------------------------------------
// transpose_w: W[1024 k][N] fp32 -> WT[N][1024 k] bf16, 64x64 tiles via LDS
// ---------------------------------------------------------------------------
__global__ __launch_bounds__(256) void transpose_w_kernel(
    const float* __restrict__ W, short* __restrict__ WT, int N)
{
    __shared__ short T[64][72];   // 144 B rows (16B-aligned)
    int nt = blockIdx.x * 64, kt = blockIdx.y * 64;
    int tid = threadIdx.x;
    int kl = tid >> 4;            // 0..15
    int nl = (tid & 15) * 4;      // 0..60
    #pragma unroll
    for (int rr = 0; rr < 4; ++rr) {
        int k = kl + rr * 16;
        float4 v = *(const float4*)(W + (size_t)(kt + k) * N + nt + nl);
        T[nl + 0][k] = f2bf(v.x);
        T[nl + 1][k] = f2bf(v.y);
        T[nl + 2][k] = f2bf(v.z);
        T[nl + 3][k] = f2bf(v.w);
    }
    __syncthreads();
    int nr = tid >> 2;            // 0..63
    int kc = (tid & 3) * 16;      // 0,16,32,48
    uint4 a = *(const uint4*)&T[nr][kc];
    uint4 b = *(const uint4*)&T[nr][kc + 8];
    short* dst = WT + (size_t)(nt + nr) * 1024 + kt + kc;
    *(uint4*)(dst) = a;
    *(uint4*)(dst + 8) = b;
}

// ---------------------------------------------------------------------------
// pos_proj: sinusoid table @ W_pos -> qpb [H][L][64]; kp1/kp2 broadcast into
// cols 64..127 of k1cat/k2cat [B][H][L][128]
// ---------------------------------------------------------------------------
__global__ __launch_bounds__(256) void pos_proj_kernel(
    const float* __restrict__ Wpos, short* __restrict__ qpb,
    short* __restrict__ k1cat, short* __restrict__ k2cat)
{
    int bid = blockIdx.x;
    int s = bid >> 7;             // 0..2
    int l0 = (bid & 127) * 8;
    int tid = threadIdx.x;
    __shared__ float pe[8][64];

    for (int idx = tid; idx < 512; idx += 256) {
        int li = idx >> 6, t = idx & 63;
        float p = (float)(l0 + li - 512);
        int j = (t < 32) ? t : (t - 32);
        float f = expf(-0.2971077539f * (float)j);   // ln(10000)/31
        float a = p * f;
        pe[li][t] = (t < 32) ? sinf(a) : cosf(a);
    }
    __syncthreads();

    float acc[4][8] = {};
    const float* wp = Wpos + s * 1024 + tid;
    for (int t = 0; t < 64; ++t) {
        float w0 = wp[t * 3072];
        float w1 = wp[t * 3072 + 256];
        float w2 = wp[t * 3072 + 512];
        float w3 = wp[t * 3072 + 768];
        #pragma unroll
        for (int li = 0; li < 8; ++li) {
            float pv = pe[li][t];
            acc[0][li] += pv * w0; acc[1][li] += pv * w1;
            acc[2][li] += pv * w2; acc[3][li] += pv * w3;
        }
    }
    #pragma unroll
    for (int cc = 0; cc < 4; ++cc) {
        int c = tid + cc * 256;
        int h = c >> 6, d = c & 63;
        #pragma unroll
        for (int li = 0; li < 8; ++li) {
            short bv = f2bf(acc[cc][li]);
            if (s == 0) {
                qpb[((size_t)(h << 10) + l0 + li) * 64 + d] = bv;
            } else {
                short* dst = (s == 1) ? k1cat : k2cat;
                #pragma unroll
                for (int bb = 0; bb < 4; ++bb)
                    dst[((size_t)((bb * 16 + h) * 1024) + l0 + li) * 128 + 64 + d] = bv;
            }
        }
    }
}

// ---------------------------------------------------------------------------
// gemm_nt: C[M][*] = A[M][1024] bf16 @ BT[N][1024] bf16 (both row-major, K dot)
// m97 structure: 128x128 tile, BK=32, global_load_lds staging (pre-swizzled
// source), XOR-swizzled ds_read_b128, 16 MFMA / K-step, 2 barriers / K-step.
// EPI==0: scatter q->qb, k1/k2->cols 0..63 of k1cat/k2cat, v->vT
// EPI==1: linear fp32 store [M][NCOLS]
// ---------------------------------------------------------------------------
template<int EPI, int NCOLS>
__global__ __launch_bounds__(256) void gemm_nt(
    const short* __restrict__ A, const short* __restrict__ BT,
    short* __restrict__ o0, short* __restrict__ o1, short* __restrict__ o2,
    short* __restrict__ o3, float* __restrict__ of)
{
    __shared__ short As[128 * 32];
    __shared__ short Bs[128 * 32];

    int nwg = gridDim.x * gridDim.y;
    int lin = blockIdx.y * gridDim.x + blockIdx.x;
    int cpx = nwg >> 3;
    int swb = (lin & 7) * cpx + (lin >> 3);     // bijective XCD swizzle (nwg%8==0)
    int bx = swb % gridDim.x, by = swb / gridDim.x;
    int m0 = by * 128, n0 = bx * 128;

    int tid = threadIdx.x;
    int w = tid >> 6, lane = tid & 63;
    int wm = w >> 1, wn = w & 1;
    int lq = lane & 15, lg = lane >> 4;

    f32x4 zero = {0.f, 0.f, 0.f, 0.f};
    f32x4 acc[4][4];
    #pragma unroll
    for (int i = 0; i < 4; ++i)
        #pragma unroll
        for (int j = 0; j < 4; ++j) acc[i][j] = zero;

    // staging: wave w covers rows w*32..w*32+31 of the 128-row tile (2 chunks)
    int swz = (((lane & 3) ^ ((lane >> 2) & 3)) << 3);   // shorts, inverse of read swizzle
    int srow = lane >> 2;                                // 0..15 within chunk
    const short* aBase = A  + (size_t)(m0 + (w << 5) + srow) * 1024 + swz;
    const short* bBase = BT + (size_t)(n0 + (w << 5) + srow) * 1024 + swz;
    short* aDst = As + w * 1024;
    short* bDst = Bs + w * 1024;

    for (int kt = 0; kt < 1024; kt += 32) {
        __syncthreads();                    // all waves done reading prev tile
        GLDS16(aBase + kt, aDst);
        GLDS16(aBase + kt + 16 * 1024, aDst + 512);
        GLDS16(bBase + kt, bDst);
        GLDS16(bBase + kt + 16 * 1024, bDst + 512);
        __syncthreads();                    // vmcnt(0) drain -> tile visible

        s16x8 af[4], bfr[4];
        #pragma unroll
        for (int mt = 0; mt < 4; ++mt) {
            int row = wm * 64 + mt * 16 + lq;
            af[mt] = ldlds(As, (row * 64 + lg * 16) ^ ((row & 3) << 4));
        }
        #pragma unroll
        for (int nt = 0; nt < 4; ++nt) {
            int row = wn * 64 + nt * 16 + lq;
            bfr[nt] = ldlds(Bs, (row * 64 + lg * 16) ^ ((row & 3) << 4));
        }
        #pragma unroll
        for (int mt = 0; mt < 4; ++mt)
            #pragma unroll
            for (int nt = 0; nt < 4; ++nt)
                acc[mt][nt] = mfma16(af[mt], bfr[nt], acc[mt][nt]);
    }

    #pragma unroll
    for (int nt = 0; nt < 4; ++nt) {
        int n = n0 + wn * 64 + nt * 16 + lq;
        int sec = n >> 10, hd = n & 1023;
        int hh = hd >> 6, d = hd & 63;
        #pragma unroll
        for (int mt = 0; mt < 4; ++mt) {
            int mb = m0 + wm * 64 + mt * 16 + lg * 4;
            if constexpr (EPI == 1) {
                #pragma unroll
                for (int r = 0; r < 4; ++r)
                    of[(size_t)(mb + r) * NCOLS + n] = acc[mt][nt][r];
            } else {
                int b = mb >> 10, li0 = mb & 1023;
                int bh = b * 16 + hh;
                if (sec == 3) {
                    s16x4 pv;
                    #pragma unroll
                    for (int r = 0; r < 4; ++r) pv[r] = f2bf(acc[mt][nt][r]);
                    *(s16x4*)(o3 + (((size_t)(bh * 64 + d)) << 10) + li0) = pv;
                } else {
                    #pragma unroll
                    for (int r = 0; r < 4; ++r) {
                        short bv = f2bf(acc[mt][nt][r]);
                        if (sec == 0)
                            o0[((size_t)(bh << 10) + li0 + r) * 64 + d] = bv;
                        else if (sec == 1)
                            o1[((size_t)bh * 1024 + li0 + r) * 128 + d] = bv;
                        else
                            o2[((size_t)bh * 1024 + li0 + r) * 128 + d] = bv;
                    }
                }
            }
        }
    }
}

// ---------------------------------------------------------------------------
// attn: flash attention, 64 q rows / block (4 waves x 16), KVBLK=32 slabs
// staged into double-buffered LDS via global_load_lds, counted-vmcnt pipeline.
// ---------------------------------------------------------------------------
__global__ __launch_bounds__(256) void attn_kernel(
    const short* __restrict__ qb, const short* __restrict__ k1cat,
    const short* __restrict__ k2cat, const short* __restrict__ vtb,
    const short* __restrict__ qpb, const int* __restrict__ PM,
    const int* __restrict__ qmask, short* __restrict__ ctx)
{
    __shared__ short K1s[2][32 * 128];
    __shared__ short K2s[2][32 * 128];
    __shared__ short Vs[2][64 * 32];
    __shared__ int   PMs[2][64];

    int bid = blockIdx.x;
    int xg = bid & 7, jj = bid >> 3;
    int bh = xg * 8 + (jj & 7);      // XCD-clustered: one XCD works 8 bh panels
    int qt = jj >> 3;
    int b = bh >> 4, h = bh & 15;

    int w = threadIdx.x >> 6, lane = threadIdx.x & 63;
    int lq = lane & 15, lg = lane >> 4;
    int q0 = qt * 64 + w * 16;
    int q_glob = q0 + lq;

    const short* qrow  = qb  + ((size_t)bh * SEQ + q0 + lq) * DHEAD;
    const short* qprow = qpb + ((size_t)h  * SEQ + q0 + lq) * DHEAD;
    s16x8 qf0  = *(const s16x8*)(qrow + lg * 8);
    s16x8 qf1  = *(const s16x8*)(qrow + 32 + lg * 8);
    s16x8 qpf0 = *(const s16x8*)(qprow + lg * 8);
    s16x8 qpf1 = *(const s16x8*)(qprow + 32 + lg * 8);
    int qm_q = qmask[b * SEQ + q_glob] & 1;
    asm volatile("s_waitcnt vmcnt(0)" ::: "memory");

    auto STAGE = [&](int d, int K0) {
        #pragma unroll
        for (int i = 0; i < 5; ++i) {
            int g = w * 5 + i;
            if (g < 8) {
                int row = g * 4 + (lane >> 4);
                int colb = ((lane & 15) << 4) ^ ((row & 7) << 4);
                const short* src = k1cat + ((size_t)bh * 1024 + K0 + row) * 128 + (colb >> 1);
                GLDS16(src, &K1s[d][g * 512]);
            } else if (g < 16) {
                int gg = g - 8;
                int row = gg * 4 + (lane >> 4);
                int colb = ((lane & 15) << 4) ^ ((row & 7) << 4);
                const short* src = k2cat + ((size_t)bh * 1024 + K0 + row) * 128 + (colb >> 1);
                GLDS16(src, &K2s[d][gg * 512]);
            } else {
                int c = g - 16;
                int row = c * 16 + (lane >> 2);
                int colb = ((lane & 3) << 4) ^ ((row & 3) << 4);
                const short* src = vtb + ((size_t)bh * 64 + row) * 1024 + K0 + (colb >> 1);
                GLDS16(src, &Vs[d][c * 512]);
            }
        }
        if (w == 0) {
            GLDS4(PM + b * 1088 + K0 + lane, &PMs[d][0]);
        }
    };

    f32x4 zero = {0.f, 0.f, 0.f, 0.f};
    f32x4 accO[4];
    #pragma unroll
    for (int i = 0; i < 4; ++i) accO[i] = zero;
    float m_run = -1e30f, l_run = 0.f;

    int nslab = 2 * qt + 2;
    STAGE(0, 0);

    for (int t = 0; t < nslab; ++t) {
        int cur = t & 1;
        if (t + 1 < nslab) {
            STAGE(cur ^ 1, (t + 1) * 32);
            if (w == 0) asm volatile("s_waitcnt vmcnt(6)" ::: "memory");
            else        asm volatile("s_waitcnt vmcnt(5)" ::: "memory");
        } else {
            asm volatile("s_waitcnt vmcnt(0)" ::: "memory");
        }
        __builtin_amdgcn_s_barrier();
        asm volatile("" ::: "memory");

        int K0 = t * 32;
        const short* b1 = K1s[cur];
        const short* b2 = K2s[cur];

        f32x4 s1v[2], s2v[2];
        #pragma unroll
        for (int hh = 0; hh < 2; ++hh) {
            int row = hh * 16 + lq;
            int ro = row * 256 + (lg << 4);
            int sw = (row & 7) << 4;
            f32x4 tv = zero, uv = zero;
            tv = mfma16(ldlds(b1, (ro      ) ^ sw), qf0,  tv);
            tv = mfma16(ldlds(b1, (ro +  64) ^ sw), qf1,  tv);
            tv = mfma16(ldlds(b1, (ro + 128) ^ sw), qpf0, tv);
            tv = mfma16(ldlds(b1, (ro + 192) ^ sw), qpf1, tv);
            s1v[hh] = tv;
            uv = mfma16(ldlds(b2, (ro      ) ^ sw), qf0,  uv);
            uv = mfma16(ldlds(b2, (ro +  64) ^ sw), qf1,  uv);
            uv = mfma16(ldlds(b2, (ro + 128) ^ sw), qpf0, uv);
            uv = mfma16(ldlds(b2, (ro + 192) ^ sw), qpf1, uv);
            s2v[hh] = uv;
        }

        float sv[8];
        #pragma unroll
        for (int i = 0; i < 8; ++i) {
            int hh = i >> 2, r = i & 3;
            int kl = hh * 16 + lg * 4 + r;
            int k_idx = K0 + kl;
            int pm = PMs[cur][kl];
            float s = ((pm & 1) == qm_q) ? s1v[hh][r] : s2v[hh][r];
            if (k_idx > q_glob || (pm & 2)) s = -INFINITY;
            sv[i] = s;
        }
        float tm = sv[0];
        #pragma unroll
        for (int i = 1; i < 8; ++i) tm = fmaxf(tm, sv[i]);
        tm = fmaxf(tm, __shfl_xor(tm, 16));
        tm = fmaxf(tm, __shfl_xor(tm, 32));
        float m_new = fmaxf(m_run, tm);
        float scale = __expf(m_run - m_new);
        float p[8]; float ps = 0.f;
        #pragma unroll
        for (int i = 0; i < 8; ++i) { p[i] = __expf(sv[i] - m_new); ps += p[i]; }
        ps += __shfl_xor(ps, 16);
        ps += __shfl_xor(ps, 32);
        l_run = l_run * scale + ps;
        m_run = m_new;

        f32x4 scv;
        scv[0] = __shfl(scale, lg * 4 + 0);
        scv[1] = __shfl(scale, lg * 4 + 1);
        scv[2] = __shfl(scale, lg * 4 + 2);
        scv[3] = __shfl(scale, lg * 4 + 3);
        #pragma unroll
        for (int dt = 0; dt < 4; ++dt) accO[dt] *= scv;

        unsigned dA0 = pack2(p[0], p[1]);
        unsigned dA1 = pack2(p[2], p[3]);
        unsigned dB0 = pack2(p[4], p[5]);
        unsigned dB1 = pack2(p[6], p[7]);
        int sl0 = lq + ((lg & 1) << 5);
        int sl1 = sl0 + 16;
        unsigned a0 = (unsigned)__shfl((int)dA0, sl0), a1 = (unsigned)__shfl((int)dA1, sl0);
        unsigned a2 = (unsigned)__shfl((int)dA0, sl1), a3 = (unsigned)__shfl((int)dA1, sl1);
        unsigned c0 = (unsigned)__shfl((int)dB0, sl0), c1 = (unsigned)__shfl((int)dB1, sl0);
        unsigned c2 = (unsigned)__shfl((int)dB0, sl1), c3 = (unsigned)__shfl((int)dB1, sl1);
        bool hi = (lg >= 2);
        union { unsigned u[4]; s16x8 v; } pa;
        pa.u[0] = hi ? c0 : a0; pa.u[1] = hi ? c1 : a1;
        pa.u[2] = hi ? c2 : a2; pa.u[3] = hi ? c3 : a3;

        #pragma unroll
        for (int dt = 0; dt < 4; ++dt) {
            int vrow = dt * 16 + lq;
            int voff = (vrow * 64 + (lg << 4)) ^ ((vrow & 3) << 4);
            accO[dt] = mfma16(pa.v, ldlds(Vs[cur], voff), accO[dt]);
        }

        asm volatile("" ::: "memory");
        __builtin_amdgcn_s_barrier();
    }

    float inv = 1.0f / l_run;
    f32x4 invv;
    invv[0] = __shfl(inv, lg * 4 + 0);
    invv[1] = __shfl(inv, lg * 4 + 1);
    invv[2] = __shfl(inv, lg * 4 + 2);
    invv[3] = __shfl(inv, lg * 4 + 3);
    #pragma unroll
    for (int dt = 0; dt < 4; ++dt) {
        #pragma unroll
        for (int r = 0; r < 4; ++r) {
            int qo = q0 + lg * 4 + r;
            size_t off = ((size_t)(b * SEQ + qo)) * DMODEL + h * DHEAD + dt * 16 + lq;
            ctx[off] = f2bf(accO[dt][r] * invv[r]);
        }
    }
}

// ---------------------------------------------------------------------------
extern "C" void kernel_launch(void* const* d_in, const int* in_sizes, int n_in,
                              void* d_out, int out_size, void* d_ws, size_t ws_size,
                              hipStream_t stream) {
    const float* embed = (const float*)d_in[0];
    const int*   umask = (const int*)d_in[1];
    const int*   qmask = (const int*)d_in[2];
    const float* Wqkv  = (const float*)d_in[3];
    const float* Wpos  = (const float*)d_in[4];
    const float* Wfc   = (const float*)d_in[5];
    float* out = (float*)d_out;

    char* w = (char*)d_ws;
    short* qb    = (short*)(w + (0ull  << 20));  // [B][H][L][64]    8 MB
    short* vtb   = (short*)(w + (8ull  << 20));  // [B][H][64][L]    8 MB
    short* qpb   = (short*)(w + (16ull << 20));  // [H][L][64]       2 MB
    short* ctx   = (short*)(w + (18ull << 20));  // [B*L][1024]      8 MB
    short* ebf   = ctx;                          // aliased: ebf dead before attn
    short* k1cat = (short*)(w + (26ull << 20));  // [B][H][L][128]  16 MB
    short* k2cat = (short*)(w + (42ull << 20));  // [B][H][L][128]  16 MB
    int*   PM    = (int*)  (w + (58ull << 20));  // [4][1088]       ~17 KB
    short* WqkvT = (short*)(w + (59ull << 20));  // [4096][1024]     8 MB
    short* WfcT  = (short*)(w + (67ull << 20));  // [1024][1024]     2 MB

    hipLaunchKernelGGL(mask_pack_kernel, dim3(4), dim3(256), 0, stream,
                       qmask, umask, PM);
    hipLaunchKernelGGL(pos_proj_kernel, dim3(384), dim3(256), 0, stream,
                       Wpos, qpb, k1cat, k2cat);
    hipLaunchKernelGGL(convert_embed_kernel, dim3(2048), dim3(256), 0, stream,
                       embed, ebf);
    hipLaunchKernelGGL(transpose_w_kernel, dim3(64, 16), dim3(256), 0, stream,
                       Wqkv, WqkvT, 4096);
    hipLaunchKernelGGL(transpose_w_kernel, dim3(16, 16), dim3(256), 0, stream,
                       Wfc, WfcT, 1024);
    hipLaunchKernelGGL((gemm_nt<0, 4096>), dim3(32, 32), dim3(256), 0, stream,
                       ebf, WqkvT, qb, k1cat, k2cat, vtb, (float*)nullptr);
    hipLaunchKernelGGL(attn_kernel, dim3(1024), dim3(256), 0, stream,
                       qb, k1cat, k2cat, vtb, qpb, PM, qmask, ctx);
    hipLaunchKernelGGL((gemm_nt<1, 1024>), dim3(8, 32), dim3(256), 0, stream,
                       ctx, WfcT, (short*)nullptr, (short*)nullptr, (short*)nullptr,
                       (short*)nullptr, out);
}

// Round 4
// 187.339 us; speedup vs baseline: 2.4872x; 1.0760x over previous
//
#include <hip/hip_runtime.h>
#include <math.h>

#define NB 4
#define SEQ 1024
#define DMODEL 1024
#define NHEAD 16
#define DHEAD 64

typedef __attribute__((ext_vector_type(8))) short s16x8;
typedef __attribute__((ext_vector_type(4))) short s16x4;
typedef __attribute__((ext_vector_type(4))) float f32x4;

__device__ __forceinline__ short f2bf(float f) {
    union { float f; unsigned u; } x; x.f = f;
    unsigned r = x.u + 0x7fffu + ((x.u >> 16) & 1u);   // RNE
    return (short)(r >> 16);
}

__device__ __forceinline__ unsigned cvtpk(float lo, float hi) {
    unsigned r;
    asm("v_cvt_pk_bf16_f32 %0, %1, %2" : "=v"(r) : "v"(lo), "v"(hi));
    return r;   // lo -> [15:0], hi -> [31:16], RNE
}

__device__ __forceinline__ f32x4 mfma16(s16x8 a, s16x8 b, f32x4 c) {
    return __builtin_amdgcn_mfma_f32_16x16x32_bf16(a, b, c, 0, 0, 0);
}

__device__ __forceinline__ s16x8 cvt8(float4 a, float4 b) {
    s16x8 v;
    v[0] = f2bf(a.x); v[1] = f2bf(a.y); v[2] = f2bf(a.z); v[3] = f2bf(a.w);
    v[4] = f2bf(b.x); v[5] = f2bf(b.y); v[6] = f2bf(b.z); v[7] = f2bf(b.w);
    return v;
}

__device__ __forceinline__ s16x8 ldlds(const short* base, int byteoff) {
    return *(const s16x8*)((const char*)base + byteoff);
}

#define GLDS16(g, l) __builtin_amdgcn_global_load_lds( \
    (const __attribute__((address_space(1))) unsigned int*)(g), \
    (__attribute__((address_space(3))) unsigned int*)(l), 16, 0, 0)
#define GLDS4(g, l) __builtin_amdgcn_global_load_lds( \
    (const __attribute__((address_space(1))) unsigned int*)(g), \
    (__attribute__((address_space(3))) unsigned int*)(l), 4, 0, 0)

// ---------------------------------------------------------------------------
// mask_pack: PM[b][k] = qmask bit0 | (invalid << 1); 64-entry pad per batch
// ---------------------------------------------------------------------------
__global__ __launch_bounds__(256) void mask_pack_kernel(
    const int* __restrict__ qmask, const int* __restrict__ umask,
    int* __restrict__ PM)
{
    int b = blockIdx.x;
    for (int k = threadIdx.x; k < 1088; k += 256) {
        int v = 2;
        if (k < 1024)
            v = (qmask[b * 1024 + k] & 1) | ((umask[b * 1024 + k] == 0) ? 2 : 0);
        PM[b * 1088 + k] = v;
    }
}

// ---------------------------------------------------------------------------
// convert_embed: fp32 -> bf16 elementwise (8 els/thread, coalesced)
// ---------------------------------------------------------------------------
__global__ __launch_bounds__(256) void convert_embed_kernel(
    const float* __restrict__ src, short* __restrict__ dst)
{
    int i = (blockIdx.x * 256 + threadIdx.x) * 8;
    float4 a = *(const float4*)(src + i);
    float4 b = *(const float4*)(src + i + 4);
    *(s16x8*)(dst + i) = cvt8(a, b);
}

// ---------------------------------------------------------------------------
// transpose_w: W[1024 k][N] fp32 -> WT[N][1024 k] bf16, 64x64 tiles via LDS
// ---------------------------------------------------------------------------
__global__ __launch_bounds__(256) void transpose_w_kernel(
    const float* __restrict__ W, short* __restrict__ WT, int N)
{
    __shared__ short T[64][72];
    int nt = blockIdx.x * 64, kt = blockIdx.y * 64;
    int tid = threadIdx.x;
    int kl = tid >> 4;
    int nl = (tid & 15) * 4;
    #pragma unroll
    for (int rr = 0; rr < 4; ++rr) {
        int k = kl + rr * 16;
        float4 v = *(const float4*)(W + (size_t)(kt + k) * N + nt + nl);
        T[nl + 0][k] = f2bf(v.x);
        T[nl + 1][k] = f2bf(v.y);
        T[nl + 2][k] = f2bf(v.z);
        T[nl + 3][k] = f2bf(v.w);
    }
    __syncthreads();
    int nr = tid >> 2;
    int kc = (tid & 3) * 16;
    uint4 a = *(const uint4*)&T[nr][kc];
    uint4 b = *(const uint4*)&T[nr][kc + 8];
    short* dst = WT + (size_t)(nt + nr) * 1024 + kt + kc;
    *(uint4*)(dst) = a;
    *(uint4*)(dst + 8) = b;
}

// ---------------------------------------------------------------------------
// pos_proj: sinusoid table @ W_pos -> qpb [H][L][64]; kp1/kp2 broadcast into
// cols 64..127 of k1cat/k2cat [B][H][L][128]
// ---------------------------------------------------------------------------
__global__ __launch_bounds__(256) void pos_proj_kernel(
    const float* __restrict__ Wpos, short* __restrict__ qpb,
    short* __restrict__ k1cat, short* __restrict__ k2cat)
{
    int bid = blockIdx.x;
    int s = bid >> 7;
    int l0 = (bid & 127) * 8;
    int tid = threadIdx.x;
    __shared__ float pe[8][64];

    for (int idx = tid; idx < 512; idx += 256) {
        int li = idx >> 6, t = idx & 63;
        float p = (float)(l0 + li - 512);
        int j = (t < 32) ? t : (t - 32);
        float f = expf(-0.2971077539f * (float)j);   // ln(10000)/31
        float a = p * f;
        pe[li][t] = (t < 32) ? sinf(a) : cosf(a);
    }
    __syncthreads();

    float acc[4][8] = {};
    const float* wp = Wpos + s * 1024 + tid;
    for (int t = 0; t < 64; ++t) {
        float w0 = wp[t * 3072];
        float w1 = wp[t * 3072 + 256];
        float w2 = wp[t * 3072 + 512];
        float w3 = wp[t * 3072 + 768];
        #pragma unroll
        for (int li = 0; li < 8; ++li) {
            float pv = pe[li][t];
            acc[0][li] += pv * w0; acc[1][li] += pv * w1;
            acc[2][li] += pv * w2; acc[3][li] += pv * w3;
        }
    }
    #pragma unroll
    for (int cc = 0; cc < 4; ++cc) {
        int c = tid + cc * 256;
        int h = c >> 6, d = c & 63;
        #pragma unroll
        for (int li = 0; li < 8; ++li) {
            short bv = f2bf(acc[cc][li]);
            if (s == 0) {
                qpb[((size_t)(h << 10) + l0 + li) * 64 + d] = bv;
            } else {
                short* dst = (s == 1) ? k1cat : k2cat;
                #pragma unroll
                for (int bb = 0; bb < 4; ++bb)
                    dst[((size_t)((bb * 16 + h) * 1024) + l0 + li) * 128 + 64 + d] = bv;
            }
        }
    }
}

// ---------------------------------------------------------------------------
// gemm_nt: C[M][*] = A[M][1024] bf16 @ BT[N][1024] bf16; m97 structure
// ---------------------------------------------------------------------------
template<int EPI, int NCOLS>
__global__ __launch_bounds__(256) void gemm_nt(
    const short* __restrict__ A, const short* __restrict__ BT,
    short* __restrict__ o0, short* __restrict__ o1, short* __restrict__ o2,
    short* __restrict__ o3, float* __restrict__ of)
{
    __shared__ short As[128 * 32];
    __shared__ short Bs[128 * 32];

    int nwg = gridDim.x * gridDim.y;
    int lin = blockIdx.y * gridDim.x + blockIdx.x;
    int cpx = nwg >> 3;
    int swb = (lin & 7) * cpx + (lin >> 3);
    int bx = swb % gridDim.x, by = swb / gridDim.x;
    int m0 = by * 128, n0 = bx * 128;

    int tid = threadIdx.x;
    int w = tid >> 6, lane = tid & 63;
    int wm = w >> 1, wn = w & 1;
    int lq = lane & 15, lg = lane >> 4;

    f32x4 zero = {0.f, 0.f, 0.f, 0.f};
    f32x4 acc[4][4];
    #pragma unroll
    for (int i = 0; i < 4; ++i)
        #pragma unroll
        for (int j = 0; j < 4; ++j) acc[i][j] = zero;

    int swz = (((lane & 3) ^ ((lane >> 2) & 3)) << 3);
    int srow = lane >> 2;
    const short* aBase = A  + (size_t)(m0 + (w << 5) + srow) * 1024 + swz;
    const short* bBase = BT + (size_t)(n0 + (w << 5) + srow) * 1024 + swz;
    short* aDst = As + w * 1024;
    short* bDst = Bs + w * 1024;

    for (int kt = 0; kt < 1024; kt += 32) {
        __syncthreads();
        GLDS16(aBase + kt, aDst);
        GLDS16(aBase + kt + 16 * 1024, aDst + 512);
        GLDS16(bBase + kt, bDst);
        GLDS16(bBase + kt + 16 * 1024, bDst + 512);
        __syncthreads();

        s16x8 af[4], bfr[4];
        #pragma unroll
        for (int mt = 0; mt < 4; ++mt) {
            int row = wm * 64 + mt * 16 + lq;
            af[mt] = ldlds(As, (row * 64 + lg * 16) ^ ((row & 3) << 4));
        }
        #pragma unroll
        for (int nt = 0; nt < 4; ++nt) {
            int row = wn * 64 + nt * 16 + lq;
            bfr[nt] = ldlds(Bs, (row * 64 + lg * 16) ^ ((row & 3) << 4));
        }
        #pragma unroll
        for (int mt = 0; mt < 4; ++mt)
            #pragma unroll
            for (int nt = 0; nt < 4; ++nt)
                acc[mt][nt] = mfma16(af[mt], bfr[nt], acc[mt][nt]);
    }

    #pragma unroll
    for (int nt = 0; nt < 4; ++nt) {
        int n = n0 + wn * 64 + nt * 16 + lq;
        int sec = n >> 10, hd = n & 1023;
        int hh = hd >> 6, d = hd & 63;
        #pragma unroll
        for (int mt = 0; mt < 4; ++mt) {
            int mb = m0 + wm * 64 + mt * 16 + lg * 4;
            if constexpr (EPI == 1) {
                #pragma unroll
                for (int r = 0; r < 4; ++r)
                    of[(size_t)(mb + r) * NCOLS + n] = acc[mt][nt][r];
            } else {
                int b = mb >> 10, li0 = mb & 1023;
                int bh = b * 16 + hh;
                if (sec == 3) {
                    s16x4 pv;
                    #pragma unroll
                    for (int r = 0; r < 4; ++r) pv[r] = f2bf(acc[mt][nt][r]);
                    *(s16x4*)(o3 + (((size_t)(bh * 64 + d)) << 10) + li0) = pv;
                } else {
                    #pragma unroll
                    for (int r = 0; r < 4; ++r) {
                        short bv = f2bf(acc[mt][nt][r]);
                        if (sec == 0)
                            o0[((size_t)(bh << 10) + li0 + r) * 64 + d] = bv;
                        else if (sec == 1)
                            o1[((size_t)bh * 1024 + li0 + r) * 128 + d] = bv;
                        else
                            o2[((size_t)bh * 1024 + li0 + r) * 128 + d] = bv;
                    }
                }
            }
        }
    }
}

// ---------------------------------------------------------------------------
// attn: flash attention; 512 blocks = 64 bh x 8 pairs; each block handles
// q-tiles (pair, 15-pair) sequentially -> uniform 34 slabs/block.
// Double-buffered LDS staging, counted vmcnt, defer-max, cvt_pk, setprio.
// ---------------------------------------------------------------------------
__global__ __launch_bounds__(256) void attn_kernel(
    const short* __restrict__ qb, const short* __restrict__ k1cat,
    const short* __restrict__ k2cat, const short* __restrict__ vtb,
    const short* __restrict__ qpb, const int* __restrict__ PM,
    const int* __restrict__ qmask, short* __restrict__ ctx)
{
    __shared__ short K1s[2][32 * 128];
    __shared__ short K2s[2][32 * 128];
    __shared__ short Vs[2][64 * 32];
    __shared__ int   PMs[2][64];

    int bid = blockIdx.x;                 // 512 blocks
    int xg = bid & 7, jj = bid >> 3;
    int bh = xg * 8 + (jj & 7);           // XCD-clustered: 8 bh panels per XCD
    int pair = jj >> 3;                   // 0..7
    int b = bh >> 4, h = bh & 15;

    int w = threadIdx.x >> 6, lane = threadIdx.x & 63;
    int lq = lane & 15, lg = lane >> 4;

    auto STAGE = [&](int d, int K0) {
        #pragma unroll
        for (int i = 0; i < 5; ++i) {
            int g = w * 5 + i;
            if (g < 8) {
                int row = g * 4 + (lane >> 4);
                int colb = ((lane & 15) << 4) ^ ((row & 7) << 4);
                const short* src = k1cat + ((size_t)bh * 1024 + K0 + row) * 128 + (colb >> 1);
                GLDS16(src, &K1s[d][g * 512]);
            } else if (g < 16) {
                int gg = g - 8;
                int row = gg * 4 + (lane >> 4);
                int colb = ((lane & 15) << 4) ^ ((row & 7) << 4);
                const short* src = k2cat + ((size_t)bh * 1024 + K0 + row) * 128 + (colb >> 1);
                GLDS16(src, &K2s[d][gg * 512]);
            } else {
                int c = g - 16;
                int row = c * 16 + (lane >> 2);
                int colb = ((lane & 3) << 4) ^ ((row & 3) << 4);
                const short* src = vtb + ((size_t)bh * 64 + row) * 1024 + K0 + (colb >> 1);
                GLDS16(src, &Vs[d][c * 512]);
            }
        }
        if (w == 0) {
            GLDS4(PM + b * 1088 + K0 + lane, &PMs[d][0]);
        }
    };

    f32x4 zero = {0.f, 0.f, 0.f, 0.f};

    #pragma unroll 1
    for (int phase = 0; phase < 2; ++phase) {
        int qt = phase ? (15 - pair) : pair;
        int q0 = qt * 64 + w * 16;
        int q_glob = q0 + lq;

        const short* qrow  = qb  + ((size_t)bh * SEQ + q_glob) * DHEAD;
        const short* qprow = qpb + ((size_t)h  * SEQ + q_glob) * DHEAD;
        s16x8 qf0  = *(const s16x8*)(qrow + lg * 8);
        s16x8 qf1  = *(const s16x8*)(qrow + 32 + lg * 8);
        s16x8 qpf0 = *(const s16x8*)(qprow + lg * 8);
        s16x8 qpf1 = *(const s16x8*)(qprow + 32 + lg * 8);
        int qm_q = qmask[b * SEQ + q_glob] & 1;
        // drain q loads so loop vmcnt counts only staging ops
        asm volatile("s_waitcnt vmcnt(0)" ::: "memory");

        f32x4 accO[4];
        #pragma unroll
        for (int i = 0; i < 4; ++i) accO[i] = zero;
        float m_run = -1e30f, l_run = 0.f;

        int nslab = 2 * qt + 2;
        STAGE(0, 0);

        for (int t = 0; t < nslab; ++t) {
            int cur = t & 1;
            if (t + 1 < nslab) {
                STAGE(cur ^ 1, (t + 1) * 32);
                if (w == 0) asm volatile("s_waitcnt vmcnt(6)" ::: "memory");
                else        asm volatile("s_waitcnt vmcnt(5)" ::: "memory");
            } else {
                asm volatile("s_waitcnt vmcnt(0)" ::: "memory");
            }
            __builtin_amdgcn_s_barrier();
            asm volatile("" ::: "memory");

            int K0 = t * 32;
            if (K0 <= q0 + 15) {          // wave-uniform: skip fully-masked slab
                const short* b1 = K1s[cur];
                const short* b2 = K2s[cur];

                f32x4 s1v[2], s2v[2];
                __builtin_amdgcn_s_setprio(1);
                #pragma unroll
                for (int hh = 0; hh < 2; ++hh) {
                    int row = hh * 16 + lq;
                    int ro = row * 256 + (lg << 4);
                    int sw = (row & 7) << 4;
                    f32x4 tv = zero, uv = zero;
                    tv = mfma16(ldlds(b1, (ro      ) ^ sw), qf0,  tv);
                    tv = mfma16(ldlds(b1, (ro +  64) ^ sw), qf1,  tv);
                    tv = mfma16(ldlds(b1, (ro + 128) ^ sw), qpf0, tv);
                    tv = mfma16(ldlds(b1, (ro + 192) ^ sw), qpf1, tv);
                    s1v[hh] = tv;
                    uv = mfma16(ldlds(b2, (ro      ) ^ sw), qf0,  uv);
                    uv = mfma16(ldlds(b2, (ro +  64) ^ sw), qf1,  uv);
                    uv = mfma16(ldlds(b2, (ro + 128) ^ sw), qpf0, uv);
                    uv = mfma16(ldlds(b2, (ro + 192) ^ sw), qpf1, uv);
                    s2v[hh] = uv;
                }
                __builtin_amdgcn_s_setprio(0);

                float sv[8];
                #pragma unroll
                for (int i = 0; i < 8; ++i) {
                    int hh = i >> 2, r = i & 3;
                    int kl = hh * 16 + lg * 4 + r;
                    int k_idx = K0 + kl;
                    int pm = PMs[cur][kl];
                    float s = ((pm & 1) == qm_q) ? s1v[hh][r] : s2v[hh][r];
                    if (k_idx > q_glob || (pm & 2)) s = -INFINITY;
                    sv[i] = s;
                }
                float tm = sv[0];
                #pragma unroll
                for (int i = 1; i < 8; ++i) tm = fmaxf(tm, sv[i]);
                tm = fmaxf(tm, __shfl_xor(tm, 16));
                tm = fmaxf(tm, __shfl_xor(tm, 32));

                // defer-max (T13): rescale only when max grew past threshold
                if (!__all(tm <= m_run + 8.0f)) {
                    float m_new = fmaxf(m_run, tm);
                    float scale = __expf(m_run - m_new);
                    m_run = m_new;
                    l_run *= scale;
                    f32x4 scv;
                    scv[0] = __shfl(scale, lg * 4 + 0);
                    scv[1] = __shfl(scale, lg * 4 + 1);
                    scv[2] = __shfl(scale, lg * 4 + 2);
                    scv[3] = __shfl(scale, lg * 4 + 3);
                    #pragma unroll
                    for (int dt = 0; dt < 4; ++dt) accO[dt] *= scv;
                }

                float p[8]; float ps = 0.f;
                #pragma unroll
                for (int i = 0; i < 8; ++i) { p[i] = __expf(sv[i] - m_run); ps += p[i]; }
                ps += __shfl_xor(ps, 16);
                ps += __shfl_xor(ps, 32);
                l_run += ps;

                // P -> 16x16x32 A-operand layout (cvt_pk packs, T12 primitive)
                unsigned dA0 = cvtpk(p[0], p[1]);
                unsigned dA1 = cvtpk(p[2], p[3]);
                unsigned dB0 = cvtpk(p[4], p[5]);
                unsigned dB1 = cvtpk(p[6], p[7]);
                int sl0 = lq + ((lg & 1) << 5);
                int sl1 = sl0 + 16;
                unsigned a0 = (unsigned)__shfl((int)dA0, sl0), a1 = (unsigned)__shfl((int)dA1, sl0);
                unsigned a2 = (unsigned)__shfl((int)dA0, sl1), a3 = (unsigned)__shfl((int)dA1, sl1);
                unsigned c0 = (unsigned)__shfl((int)dB0, sl0), c1 = (unsigned)__shfl((int)dB1, sl0);
                unsigned c2 = (unsigned)__shfl((int)dB0, sl1), c3 = (unsigned)__shfl((int)dB1, sl1);
                bool hi = (lg >= 2);
                union { unsigned u[4]; s16x8 v; } pa;
                pa.u[0] = hi ? c0 : a0; pa.u[1] = hi ? c1 : a1;
                pa.u[2] = hi ? c2 : a2; pa.u[3] = hi ? c3 : a3;

                __builtin_amdgcn_s_setprio(1);
                #pragma unroll
                for (int dt = 0; dt < 4; ++dt) {
                    int vrow = dt * 16 + lq;
                    int voff = (vrow * 64 + (lg << 4)) ^ ((vrow & 3) << 4);
                    accO[dt] = mfma16(pa.v, ldlds(Vs[cur], voff), accO[dt]);
                }
                __builtin_amdgcn_s_setprio(0);
            }

            asm volatile("" ::: "memory");
            __builtin_amdgcn_s_barrier();
        }

        float inv = 1.0f / l_run;
        f32x4 invv;
        invv[0] = __shfl(inv, lg * 4 + 0);
        invv[1] = __shfl(inv, lg * 4 + 1);
        invv[2] = __shfl(inv, lg * 4 + 2);
        invv[3] = __shfl(inv, lg * 4 + 3);
        #pragma unroll
        for (int dt = 0; dt < 4; ++dt) {
            #pragma unroll
            for (int r = 0; r < 4; ++r) {
                int qo = q0 + lg * 4 + r;
                size_t off = ((size_t)(b * SEQ + qo)) * DMODEL + h * DHEAD + dt * 16 + lq;
                ctx[off] = f2bf(accO[dt][r] * invv[r]);
            }
        }
    }
}

// ---------------------------------------------------------------------------
extern "C" void kernel_launch(void* const* d_in, const int* in_sizes, int n_in,
                              void* d_out, int out_size, void* d_ws, size_t ws_size,
                              hipStream_t stream) {
    const float* embed = (const float*)d_in[0];
    const int*   umask = (const int*)d_in[1];
    const int*   qmask = (const int*)d_in[2];
    const float* Wqkv  = (const float*)d_in[3];
    const float* Wpos  = (const float*)d_in[4];
    const float* Wfc   = (const float*)d_in[5];
    float* out = (float*)d_out;

    char* w = (char*)d_ws;
    short* qb    = (short*)(w + (0ull  << 20));  // [B][H][L][64]    8 MB
    short* vtb   = (short*)(w + (8ull  << 20));  // [B][H][64][L]    8 MB
    short* qpb   = (short*)(w + (16ull << 20));  // [H][L][64]       2 MB
    short* ctx   = (short*)(w + (18ull << 20));  // [B*L][1024]      8 MB
    short* ebf   = ctx;                          // aliased: ebf dead before attn
    short* k1cat = (short*)(w + (26ull << 20));  // [B][H][L][128]  16 MB
    short* k2cat = (short*)(w + (42ull << 20));  // [B][H][L][128]  16 MB
    int*   PM    = (int*)  (w + (58ull << 20));  // [4][1088]       ~17 KB
    short* WqkvT = (short*)(w + (59ull << 20));  // [4096][1024]     8 MB
    short* WfcT  = (short*)(w + (67ull << 20));  // [1024][1024]     2 MB

    hipLaunchKernelGGL(mask_pack_kernel, dim3(4), dim3(256), 0, stream,
                       qmask, umask, PM);
    hipLaunchKernelGGL(pos_proj_kernel, dim3(384), dim3(256), 0, stream,
                       Wpos, qpb, k1cat, k2cat);
    hipLaunchKernelGGL(convert_embed_kernel, dim3(2048), dim3(256), 0, stream,
                       embed, ebf);
    hipLaunchKernelGGL(transpose_w_kernel, dim3(64, 16), dim3(256), 0, stream,
                       Wqkv, WqkvT, 4096);
    hipLaunchKernelGGL(transpose_w_kernel, dim3(16, 16), dim3(256), 0, stream,
                       Wfc, WfcT, 1024);
    hipLaunchKernelGGL((gemm_nt<0, 4096>), dim3(32, 32), dim3(256), 0, stream,
                       ebf, WqkvT, qb, k1cat, k2cat, vtb, (float*)nullptr);
    hipLaunchKernelGGL(attn_kernel, dim3(512), dim3(256), 0, stream,
                       qb, k1cat, k2cat, vtb, qpb, PM, qmask, ctx);
    hipLaunchKernelGGL((gemm_nt<1, 1024>), dim3(8, 32), dim3(256), 0, stream,
                       ctx, WfcT, (short*)nullptr, (short*)nullptr, (short*)nullptr,
                       (short*)nullptr, out);
}